// Round 1
// baseline (951.357 us; speedup 1.0000x reference)
//
#include <hip/hip_runtime.h>

#define BT 256
#define HID 2048
#define NE 8
#define INTER 4096

typedef short short8 __attribute__((ext_vector_type(8)));
typedef float f32x4 __attribute__((ext_vector_type(4)));

__device__ inline unsigned short f2bf(float f){
  unsigned int u = __float_as_uint(f);
  u += 0x7fff + ((u >> 16) & 1);   // RNE
  return (unsigned short)(u >> 16);
}
__device__ inline unsigned int pk2(float x, float y){
  return (unsigned int)f2bf(x) | ((unsigned int)f2bf(y) << 16);
}
__device__ inline short8 cvt8(float4 a, float4 b){
  union { unsigned int u[4]; short8 s; } r;
  r.u[0] = pk2(a.x, a.y); r.u[1] = pk2(a.z, a.w);
  r.u[2] = pk2(b.x, b.y); r.u[3] = pk2(b.z, b.w);
  return r.s;
}

// async 16B global->LDS DMA; dest must be linear base+lane*16 (rule #21),
// swizzle achieved by pre-swizzling the per-lane GLOBAL source address.
__device__ inline void glds16(const void* g, void* l){
  __builtin_amdgcn_global_load_lds(
      (const __attribute__((address_space(1))) unsigned int*)g,
      (__attribute__((address_space(3))) unsigned int*)l, 16, 0, 0);
}

// bf16 LDS tile, rows of 64 elems; 8 chunks of 8 elems; chunk' = chunk ^ (row&7)
__device__ inline short8 fragh(const unsigned short* tile, int row, int kbase){
  int cp = (kbase >> 3) ^ (row & 7);
  return *(const short8*)(tile + row*64 + cp*8);
}

// ---------------- routing ----------------
__global__ void routing_kernel(const int* __restrict__ sel, const float* __restrict__ rw,
                               int* counts, int* bases, int* tokl, float* wtl){
  __shared__ int cnt[NE]; __shared__ int bs[NE]; __shared__ int cur[NE];
  int t = threadIdx.x;
  if (t < NE) cnt[t] = 0;
  __syncthreads();
  int s0 = sel[2*t], s1 = sel[2*t+1];
  float w0 = rw[2*t], w1 = rw[2*t+1];
  bool dup = (s0 == s1);
  atomicAdd(&cnt[s1], 1);
  if (!dup) atomicAdd(&cnt[s0], 1);
  __syncthreads();
  if (t == 0){ int a = 0; for (int e = 0; e < NE; e++){ bs[e] = a; cur[e] = a; a += cnt[e]; } }
  __syncthreads();
  int slot = atomicAdd(&cur[s1], 1); tokl[slot] = t; wtl[slot] = w1;
  if (!dup){ slot = atomicAdd(&cur[s0], 1); tokl[slot] = t; wtl[slot] = w0; }
  if (t < NE){ counts[t] = cnt[t]; bases[t] = bs[t]; }
}

// ---------------- gather: hs -> slot-ordered bf16 matrix ----------------
// one block per slot row; 2048 fp32 -> 2048 bf16
__global__ void gather_kernel(const float* __restrict__ hs, const int* __restrict__ tokl,
                              const int* __restrict__ counts, const int* __restrict__ bases,
                              unsigned short* __restrict__ hsg){
  int b = blockIdx.x;
  int total = bases[NE-1] + counts[NE-1];
  if (b >= total) return;
  int tok = tokl[b];
  const float4* src = (const float4*)(hs + (size_t)tok * HID);
  short8* dst = (short8*)(hsg + (size_t)b * HID);
  int t = threadIdx.x;
  dst[t] = cvt8(src[2*t], src[2*t+1]);
}

// ---------------- gemm1: up/gate = hsg @ w13^T, cur = silu(up)*gate ----------------
// grid (INTER/64=64, 2, NE). Tile M=128, N=64 i-cols x {up,gate}=128 B-rows, Ktile=64.
// LDS: Ah 2x16KB bf16 + Bh 2x16KB bf16 = 64KB -> 2 blocks/CU.
// 2-phase pipeline: prefetch tile t+1 (A via glds16, B via regs) while MFMA on tile t.
__global__ __launch_bounds__(256, 2) void gemm1_kernel(
    const unsigned short* __restrict__ hsg, const float* __restrict__ w13,
    const int* __restrict__ counts, const int* __restrict__ bases,
    unsigned short* __restrict__ cur)
{
  const int e = blockIdx.z;
  const int cnt = counts[e];
  const int mtile = blockIdx.y;
  if (mtile * 128 >= cnt) return;
  const int f0 = blockIdx.x * 64;
  const int base = bases[e];
  const int tid = threadIdx.x;

  __shared__ __align__(16) unsigned short Ah[2][128*64];  // 2 x 16 KB
  __shared__ __align__(16) unsigned short Bh[2][128*64];  // 2 x 16 KB

  // A: 4 glds16 regions of 4 KB; linear LDS dest, pre-swizzled global source
  const unsigned short* gA[4]; int offA[4];
#pragma unroll
  for (int r = 0; r < 4; r++){
    int off = r*4096 + tid*16;
    int row = off >> 7;                 // 128 B per bf16 row
    int cp  = (off >> 4) & 7;
    int col = (cp ^ (row & 7)) * 8;     // bf16 elems
    int slot = mtile*128 + row; if (slot >= cnt) slot = cnt - 1;
    gA[r] = hsg + (size_t)(base + slot) * HID + col;
    offA[r] = off;
  }
  // B: reg-staged fp32 -> bf16; thread owns 4 x 16B bf16 chunks (= 4 x 8 fp32 src)
  const float* gB[4]; int offB[4];
#pragma unroll
  for (int r = 0; r < 4; r++){
    int off = r*4096 + tid*16;
    int row = off >> 7;
    int cp  = (off >> 4) & 7;
    int col = (cp ^ (row & 7)) * 8;
    int wrow = (row < 64) ? (f0 + row) : (INTER + f0 + row - 64);
    gB[r] = w13 + (size_t)e * 2*INTER*HID + (size_t)wrow * HID + col;
    offB[r] = off;
  }

  const int wv = tid >> 6, wm = wv >> 1, wn = wv & 1;
  const int lane = tid & 63;
  const int lrow = lane & 15, quad = lane >> 4;

  f32x4 acc[2][4][2];   // [s][mf][nt]
#pragma unroll
  for (int s=0;s<2;s++)
#pragma unroll
    for (int mf=0;mf<4;mf++)
#pragma unroll
      for (int nt=0;nt<2;nt++) acc[s][mf][nt] = (f32x4){0.f,0.f,0.f,0.f};

  float4 bv[4][2];
  // prologue: stage tile 0 into buffer 0
#pragma unroll
  for (int r = 0; r < 4; r++) glds16(gA[r], (char*)Ah[0] + offA[r]);
#pragma unroll
  for (int r = 0; r < 4; r++){ bv[r][0] = *(const float4*)(gB[r]); bv[r][1] = *(const float4*)(gB[r] + 4); }
#pragma unroll
  for (int r = 0; r < 4; r++) *(short8*)((char*)Bh[0] + offB[r]) = cvt8(bv[r][0], bv[r][1]);
  asm volatile("s_waitcnt vmcnt(0) lgkmcnt(0)" ::: "memory");
  __builtin_amdgcn_s_barrier();
  __builtin_amdgcn_sched_barrier(0);

  int cb = 0;
  for (int t = 0; t < HID/64; ++t){
    const int nb = cb ^ 1;
    const bool pf = (t + 1 < HID/64);
    const int kn = (t + 1) * 64;
    if (pf){
#pragma unroll
      for (int r = 0; r < 4; r++) glds16(gA[r] + kn, (char*)Ah[nb] + offA[r]);
#pragma unroll
      for (int r = 0; r < 4; r++){ bv[r][0] = *(const float4*)(gB[r] + kn); bv[r][1] = *(const float4*)(gB[r] + kn + 4); }
    }
#pragma unroll
    for (int ks = 0; ks < 64; ks += 32){
      const int kb = ks + quad*8;
      short8 a[4], b[2][2];
#pragma unroll
      for (int mf=0;mf<4;mf++) a[mf] = fragh(Ah[cb], wm*64 + mf*16 + lrow, kb);
#pragma unroll
      for (int s=0;s<2;s++)
#pragma unroll
        for (int nt=0;nt<2;nt++)
          b[s][nt] = fragh(Bh[cb], s*64 + wn*32 + nt*16 + lrow, kb);
#pragma unroll
      for (int s=0;s<2;s++)
#pragma unroll
        for (int mf=0;mf<4;mf++)
#pragma unroll
          for (int nt=0;nt<2;nt++)
            acc[s][mf][nt] = __builtin_amdgcn_mfma_f32_16x16x32_bf16(
                a[mf], b[s][nt], acc[s][mf][nt], 0,0,0);
    }
    if (pf){
#pragma unroll
      for (int r = 0; r < 4; r++) *(short8*)((char*)Bh[nb] + offB[r]) = cvt8(bv[r][0], bv[r][1]);
    }
    asm volatile("s_waitcnt vmcnt(0) lgkmcnt(0)" ::: "memory");
    __builtin_amdgcn_s_barrier();
    __builtin_amdgcn_sched_barrier(0);
    cb = nb;
  }

  // epilogue: silu(up)*gate -> bf16 cur
#pragma unroll
  for (int mf = 0; mf < 4; mf++){
#pragma unroll
    for (int reg = 0; reg < 4; reg++){
      int m = mtile*128 + wm*64 + mf*16 + quad*4 + reg;
      if (m >= cnt) continue;
      size_t rowoff = (size_t)(base + m) * INTER;
#pragma unroll
      for (int nt = 0; nt < 2; nt++){
        int i = f0 + wn*32 + nt*16 + lrow;
        float up   = acc[0][mf][nt][reg];
        float gate = acc[1][mf][nt][reg];
        float sv = up / (1.f + __expf(-up));
        cur[rowoff + i] = f2bf(sv * gate);
      }
    }
  }
}

// ---------------- gemm2: out += w * (cur @ w2^T) ----------------
// grid (HID/32=64, 2, NE). Tile M=128, H=32, K=4096 (no split-K), Ktile=64.
// LDS: Ah 2x16KB bf16 + Bh 2x4KB bf16 = 40KB. Same 2-phase pipeline.
__global__ __launch_bounds__(256, 3) void gemm2_kernel(
    const unsigned short* __restrict__ cur, const float* __restrict__ w2,
    const int* __restrict__ counts, const int* __restrict__ bases,
    const int* __restrict__ tokl, const float* __restrict__ wtl,
    float* __restrict__ out)
{
  const int e = blockIdx.z;
  const int cnt = counts[e];
  const int mtile = blockIdx.y;
  if (mtile * 128 >= cnt) return;
  const int h0 = blockIdx.x * 32;
  const int base = bases[e];
  const int tid = threadIdx.x;

  __shared__ __align__(16) unsigned short Ah[2][128*64]; // 2 x 16 KB
  __shared__ __align__(16) unsigned short Bh[2][32*64];  // 2 x 4 KB

  const unsigned short* gA[4]; int offA[4];
#pragma unroll
  for (int r = 0; r < 4; r++){
    int off = r*4096 + tid*16;
    int row = off >> 7;
    int cp  = (off >> 4) & 7;
    int col = (cp ^ (row & 7)) * 8;
    int slot = mtile*128 + row; if (slot >= cnt) slot = cnt - 1;
    gA[r] = cur + (size_t)(base + slot) * INTER + col;
    offA[r] = off;
  }
  const float* gB; int offB;
  {
    int off = tid*16;                  // 4 KB tile: one 16B chunk per thread
    int row = off >> 7;
    int cp  = (off >> 4) & 7;
    int col = (cp ^ (row & 7)) * 8;
    gB = w2 + (size_t)e * HID * INTER + (size_t)(h0 + row) * INTER + col;
    offB = off;
  }

  const int wv = tid >> 6, wm = wv >> 1, wn = wv & 1;
  const int lane = tid & 63;
  const int lrow = lane & 15, quad = lane >> 4;

  f32x4 acc[4];
#pragma unroll
  for (int mf=0;mf<4;mf++) acc[mf] = (f32x4){0.f,0.f,0.f,0.f};

  float4 bv0, bv1;
  // prologue
#pragma unroll
  for (int r = 0; r < 4; r++) glds16(gA[r], (char*)Ah[0] + offA[r]);
  bv0 = *(const float4*)gB; bv1 = *(const float4*)(gB + 4);
  *(short8*)((char*)Bh[0] + offB) = cvt8(bv0, bv1);
  asm volatile("s_waitcnt vmcnt(0) lgkmcnt(0)" ::: "memory");
  __builtin_amdgcn_s_barrier();
  __builtin_amdgcn_sched_barrier(0);

  int cb = 0;
  for (int t = 0; t < INTER/64; ++t){
    const int nb = cb ^ 1;
    const bool pf = (t + 1 < INTER/64);
    const int kn = (t + 1) * 64;
    if (pf){
#pragma unroll
      for (int r = 0; r < 4; r++) glds16(gA[r] + kn, (char*)Ah[nb] + offA[r]);
      bv0 = *(const float4*)(gB + kn); bv1 = *(const float4*)(gB + kn + 4);
    }
#pragma unroll
    for (int ks = 0; ks < 64; ks += 32){
      const int kb = ks + quad*8;
      short8 a[4], b;
#pragma unroll
      for (int mf=0;mf<4;mf++) a[mf] = fragh(Ah[cb], wm*64 + mf*16 + lrow, kb);
      b = fragh(Bh[cb], wn*16 + lrow, kb);
#pragma unroll
      for (int mf=0;mf<4;mf++)
        acc[mf] = __builtin_amdgcn_mfma_f32_16x16x32_bf16(a[mf], b, acc[mf], 0,0,0);
    }
    if (pf) *(short8*)((char*)Bh[nb] + offB) = cvt8(bv0, bv1);
    asm volatile("s_waitcnt vmcnt(0) lgkmcnt(0)" ::: "memory");
    __builtin_amdgcn_s_barrier();
    __builtin_amdgcn_sched_barrier(0);
    cb = nb;
  }

#pragma unroll
  for (int mf = 0; mf < 4; mf++){
#pragma unroll
    for (int reg = 0; reg < 4; reg++){
      int m = mtile*128 + wm*64 + mf*16 + quad*4 + reg;
      if (m >= cnt) continue;
      int tk  = tokl[base + m];
      float w = wtl[base + m];
      int h = h0 + wn*16 + lrow;
      atomicAdd(&out[(size_t)tk * HID + h], w * acc[mf][reg]);
    }
  }
}

extern "C" void kernel_launch(void* const* d_in, const int* in_sizes, int n_in,
                              void* d_out, int out_size, void* d_ws, size_t ws_size,
                              hipStream_t stream){
  const float* hs  = (const float*)d_in[0];
  const int*   sel = (const int*)d_in[1];
  const float* rw  = (const float*)d_in[2];
  const float* w13 = (const float*)d_in[3];
  const float* w2  = (const float*)d_in[4];
  float* out = (float*)d_out;
  char* ws = (char*)d_ws;

  int* counts = (int*)ws;                  // 8
  int* bases  = counts + 8;                // 8
  int* tokl   = bases + 8;                 // 512
  float* wtl  = (float*)(tokl + 512);      // 512
  unsigned short* hsg = (unsigned short*)(ws + 8192);                        // 512*2048 bf16 = 2 MiB
  unsigned short* cur = (unsigned short*)(ws + 8192 + (size_t)512*HID*2);    // 512*4096 bf16 = 4 MiB

  hipMemsetAsync(d_out, 0, (size_t)BT * HID * sizeof(float), stream);
  routing_kernel<<<1, 256, 0, stream>>>(sel, rw, counts, bases, tokl, wtl);
  gather_kernel<<<512, 256, 0, stream>>>(hs, tokl, counts, bases, hsg);
  dim3 g1(INTER/64, 2, NE);
  gemm1_kernel<<<g1, 256, 0, stream>>>(hsg, w13, counts, bases, cur);
  dim3 g2(HID/32, 2, NE);
  gemm2_kernel<<<g2, 256, 0, stream>>>(cur, w2, counts, bases, tokl, wtl, out);
}